// Round 6
// baseline (13.590 us; speedup 1.0000x reference)
//
#include <hip/hip_runtime.h>
#include <hip/hip_bf16.h>

// Problem: B=8, L=4096, H=1024, K=512
// out[b,s,t] = col[b,s] = dot(seq[b, src_pos[b][s], :], w[:H])
//                       + dot(seq[b, tgt_pos[b][s], :], w[H:]) + bias
// Single dispatch: 512 blocks x 512 threads (8 waves). Each block owns
// (b, group of 8 s). Block cooperatively: stages weight (8KB) into LDS,
// derives the 16 needed mask positions (packed scan), then each wave does
// one dual dot (rows from global, weights from LDS) + 2KB broadcast write.

#define L_DIM 4096
#define H_DIM 1024
#define K_DIM 512
#define B_DIM 8
#define PACKED_K (K_DIM | (K_DIM << 16))

typedef float f32x4 __attribute__((ext_vector_type(4)));

// 4 bytes (any-nonzero) -> 4-bit movemask, robust to 0/1 or 0/255 encodings
__device__ __forceinline__ unsigned nib4(unsigned w) {
    unsigned x = w | (w >> 4); x |= x >> 2; x |= x >> 1; x &= 0x01010101u;
    return ((x * 0x01020408u) >> 24) & 0xFu;
}
// position of n-th (0-based) set bit of m (<=16 bits)
__device__ __forceinline__ int nth16(unsigned m, int n) {
    int pos = 0, c;
    c = __popc(m & 0xFFu); if (n >= c) { n -= c; pos += 8; m >>= 8; }
    c = __popc(m & 0xFu);  if (n >= c) { n -= c; pos += 4; m >>= 4; }
    c = __popc(m & 0x3u);  if (n >= c) { n -= c; pos += 2; m >>= 2; }
    c = (int)(m & 1u);     if (n >= c) { pos += 1; }
    return pos;
}

__global__ __launch_bounds__(512) void fused_kernel(
    const float* __restrict__ seq,
    const void* __restrict__ smask, const void* __restrict__ tmask,
    const float* __restrict__ weight, const float* __restrict__ bias,
    float* __restrict__ out)
{
    const int tid  = threadIdx.x;      // 0..511
    const int wid  = tid >> 6;         // wave in block, 0..7
    const int lane = tid & 63;
    const int bb   = blockIdx.x;       // 0..511
    const int b    = bb >> 6;          // batch
    const int sg   = (bb & 63) << 3;   // base s of this block's 8 ranks

    __shared__ f32x4 wLds[512];        // 8KB: w1 in [0..255], w2 in [256..511]
    __shared__ int wtot[8];
    __shared__ int posLds[16];         // [0..7]=src pos, [8..15]=tgt pos

    // ---- stage weight into LDS (overlaps with probe) ----
    wLds[tid] = ((const f32x4*)weight)[tid];

    // ---- cooperative probe: thread covers bytes [tid*8, tid*8+8) ----
    const uint2* sb = (const uint2*)((const unsigned char*)smask + (size_t)b * L_DIM);
    const uint2* tb = (const uint2*)((const unsigned char*)tmask + (size_t)b * L_DIM);
    uint2 us = sb[tid], ut = tb[tid];
    unsigned mS = nib4(us.x) | (nib4(us.y) << 4);
    unsigned mT = nib4(ut.x) | (nib4(ut.y) << 4);
    int packed = __popc(mS) | (__popc(mT) << 16);

    int x = packed;                     // wave-inclusive scan (packed both masks)
#pragma unroll
    for (int off = 1; off < 64; off <<= 1) {
        int y = __shfl_up(x, off, 64);
        if (lane >= off) x += y;
    }
    if (lane == 63) wtot[wid] = x;
    __syncthreads();
    int off_ = 0, tot = 0;
#pragma unroll
    for (int w = 0; w < 8; ++w) { int v = wtot[w]; tot += v; if (w < wid) off_ += v; }
    x += off_;

    if (tot != PACKED_K) {              // block-uniform: masks are int32, redo
        __syncthreads();                // protect wtot before rewrite
        const uint4* si = (const uint4*)((const unsigned*)smask + (size_t)b * L_DIM) + tid * 2;
        const uint4* ti = (const uint4*)((const unsigned*)tmask + (size_t)b * L_DIM) + tid * 2;
        mS = 0u; mT = 0u;
#pragma unroll
        for (int j = 0; j < 2; ++j) {
            uint4 u = si[j], v = ti[j];
            const int base = j * 4;
            mS |= (((u.x != 0) ? 1u : 0u) << base) | (((u.y != 0) ? 1u : 0u) << (base + 1))
                | (((u.z != 0) ? 1u : 0u) << (base + 2)) | (((u.w != 0) ? 1u : 0u) << (base + 3));
            mT |= (((v.x != 0) ? 1u : 0u) << base) | (((v.y != 0) ? 1u : 0u) << (base + 1))
                | (((v.z != 0) ? 1u : 0u) << (base + 2)) | (((v.w != 0) ? 1u : 0u) << (base + 3));
        }
        packed = __popc(mS) | (__popc(mT) << 16);
        x = packed;
#pragma unroll
        for (int off = 1; off < 64; off <<= 1) {
            int y = __shfl_up(x, off, 64);
            if (lane >= off) x += y;
        }
        if (lane == 63) wtot[wid] = x;
        __syncthreads();
        off_ = 0;
#pragma unroll
        for (int w = 0; w < 8; ++w) { int v = wtot[w]; if (w < wid) off_ += v; }
        x += off_;
    }

    const int exc  = x - packed;        // exclusive prefix, packed
    const int excS = exc & 0xffff, excT = exc >> 16;  // fields never carry (<=512)
    const int cntS = __popc(mS), cntT = __popc(mT);
#pragma unroll
    for (int j = 0; j < 8; ++j) {
        const int s = sg + j;
        if (s >= excS && s < excS + cntS) posLds[j]     = tid * 8 + nth16(mS, s - excS);
        if (s >= excT && s < excT + cntT) posLds[8 + j] = tid * 8 + nth16(mT, s - excT);
    }
    __syncthreads();                    // covers posLds AND wLds

    // ---- per-wave dual dot: rows from global, weights from LDS ----
    const int ps = posLds[wid];
    const int pt = posLds[8 + wid];

    const float4* __restrict__ srow = (const float4*)(seq + ((size_t)b * L_DIM + ps) * H_DIM);
    const float4* __restrict__ trow = (const float4*)(seq + ((size_t)b * L_DIM + pt) * H_DIM);

    float acc0 = 0.f, acc1 = 0.f;
#pragma unroll
    for (int j = 0; j < 4; ++j) {
        const int i = lane + 64 * j;
        float4 a = srow[i], c = trow[i];
        f32x4 wa = wLds[i], wc = wLds[256 + i];
        acc0 += a.x * wa.x + a.y * wa.y + a.z * wa.z + a.w * wa.w;
        acc1 += c.x * wc.x + c.y * wc.y + c.z * wc.z + c.w * wc.w;
    }
    float acc = acc0 + acc1;
#pragma unroll
    for (int off = 32; off; off >>= 1) acc += __shfl_xor(acc, off, 64);

    const float col = acc + bias[0];
    const f32x4 v = {col, col, col, col};
    f32x4* orow = (f32x4*)(out + ((size_t)(b * K_DIM + sg + wid)) * K_DIM);
    orow[lane] = v;
    orow[lane + 64] = v;
}

extern "C" void kernel_launch(void* const* d_in, const int* in_sizes, int n_in,
                              void* d_out, int out_size, void* d_ws, size_t ws_size,
                              hipStream_t stream) {
    const float* seq    = (const float*)d_in[0];
    const void*  smask  = d_in[1];
    const void*  tmask  = d_in[2];
    const float* weight = (const float*)d_in[3];
    const float* bias   = (const float*)d_in[4];
    float* out = (float*)d_out;
    (void)d_ws; (void)ws_size;

    fused_kernel<<<512, 512, 0, stream>>>(seq, smask, tmask, weight, bias, out);
}